// Round 1
// baseline (256.447 us; speedup 1.0000x reference)
//
#include <hip/hip_runtime.h>
#include <math.h>

// B=8, T=4096, D=1024, ALG=16, n=64 chunks/row.
// out = x + gate * ( sb * sum_s wedge_s  +  e0 * ss * sum_s scalar_s )
//   c_s = x[t] - x[(t-s) mod T]   (per batch row), s in {1,2,4}
//   scalar_s = sum_d w[d%16] * x_d * c_d   with w = C0 diagonal
//   wedge blades per 16-chunk: k=3:(1,2) k=5:(1,4) k=6:(2,4) k=9:(1,8) k=10:(2,8) k=12:(4,8)
//     wedge_k = x_i*c_j - x_j*c_i  (sign +1, i = lower bit)
// One wave (64 lanes) per (b,t) row; lane = one 16-float chunk. Reductions are
// wave-level shuffles only (wave==row). No LDS, no __syncthreads.

constexpr int T_DIM = 4096;
constexpr int D_DIM = 1024;
constexpr int ROWS_PER_BLOCK = 4;   // 256 threads / 64 lanes

__device__ __forceinline__ float sigmoidf(float z) {
    return 1.0f / (1.0f + expf(-z));
}

__global__ __launch_bounds__(256) void clifford_kernel(
    const float* __restrict__ x,
    const float* __restrict__ gate_w,
    const float* __restrict__ gate_b,
    const float* __restrict__ scalar_w,
    const float* __restrict__ bivec_w,
    float* __restrict__ out,
    int BT)
{
    const int lane = threadIdx.x & 63;
    const int row  = blockIdx.x * ROWS_PER_BLOCK + (threadIdx.x >> 6);
    if (row >= BT) return;
    const int b = row >> 12;            // row / 4096
    const int t = row & (T_DIM - 1);

    const float ss = sigmoidf(scalar_w[0]);
    const float sb = sigmoidf(bivec_w[0]);
    const float gb = gate_b[0];

    const float* __restrict__ xrow = x + (size_t)row * D_DIM;
    const int base = lane << 4;         // chunk offset within row

    // ---- load this lane's 16-float chunk of x and gate_w ----
    float xa[16], gw[16];
    #pragma unroll
    for (int j = 0; j < 4; ++j) {
        *(float4*)(&xa[4 * j]) = *(const float4*)(xrow + base + 4 * j);
        *(float4*)(&gw[4 * j]) = *(const float4*)(gate_w + base + 4 * j);
    }

    // gate partial dot
    float gate_part = 0.0f;
    #pragma unroll
    for (int i = 0; i < 16; ++i) gate_part += xa[i] * gw[i];

    // blade weights for the scalar (C0 diagonal), metric [1,1,1,-1]
    const float w_blade[16] = { 1.f, 1.f, 1.f,-1.f,  1.f,-1.f,-1.f,-1.f,
                               -1.f, 1.f, 1.f, 1.f,  1.f, 1.f, 1.f,-1.f };

    float sc_part = 0.0f;               // scalar partial, summed over all 3 shifts
    float wacc[6] = {0.f,0.f,0.f,0.f,0.f,0.f};  // k = 3,5,6,9,10,12

    #pragma unroll
    for (int si = 0; si < 3; ++si) {
        const int s  = 1 << si;
        const int tp = (t - s) & (T_DIM - 1);
        const float* __restrict__ prow = x + ((size_t)b * T_DIM + tp) * D_DIM;

        float ca[16];
        #pragma unroll
        for (int j = 0; j < 4; ++j) {
            float4 p = *(const float4*)(prow + base + 4 * j);
            ca[4*j+0] = xa[4*j+0] - p.x;
            ca[4*j+1] = xa[4*j+1] - p.y;
            ca[4*j+2] = xa[4*j+2] - p.z;
            ca[4*j+3] = xa[4*j+3] - p.w;
        }

        #pragma unroll
        for (int i = 0; i < 16; ++i) sc_part += w_blade[i] * xa[i] * ca[i];

        wacc[0] += xa[1] * ca[2] - xa[2] * ca[1];   // k=3  (e12)
        wacc[1] += xa[1] * ca[4] - xa[4] * ca[1];   // k=5  (e13)
        wacc[2] += xa[2] * ca[4] - xa[4] * ca[2];   // k=6  (e23)
        wacc[3] += xa[1] * ca[8] - xa[8] * ca[1];   // k=9  (e14)
        wacc[4] += xa[2] * ca[8] - xa[8] * ca[2];   // k=10 (e24)
        wacc[5] += xa[4] * ca[8] - xa[8] * ca[4];   // k=12 (e34)
    }

    // ---- wave-level butterfly reductions over the 64 lanes of this row ----
    #pragma unroll
    for (int off = 32; off > 0; off >>= 1) {
        gate_part += __shfl_xor(gate_part, off, 64);
        sc_part   += __shfl_xor(sc_part,   off, 64);
    }
    const float gate = sigmoidf(gate_part + gb);

    // ---- epilogue: out = x + gate * delta ----
    float o[16];
    #pragma unroll
    for (int i = 0; i < 16; ++i) o[i] = xa[i];
    const float gsb = gate * sb;
    o[3]  += gsb * wacc[0];
    o[5]  += gsb * wacc[1];
    o[6]  += gsb * wacc[2];
    o[9]  += gsb * wacc[3];
    o[10] += gsb * wacc[4];
    o[12] += gsb * wacc[5];
    if (lane == 0) o[0] += gate * ss * sc_part;   // d==0 of this row

    float* __restrict__ orow = out + (size_t)row * D_DIM;
    #pragma unroll
    for (int j = 0; j < 4; ++j)
        *(float4*)(orow + base + 4 * j) = *(const float4*)(&o[4 * j]);
}

extern "C" void kernel_launch(void* const* d_in, const int* in_sizes, int n_in,
                              void* d_out, int out_size, void* d_ws, size_t ws_size,
                              hipStream_t stream) {
    const float* x  = (const float*)d_in[0];
    const float* gw = (const float*)d_in[1];
    const float* gb = (const float*)d_in[2];
    const float* sw = (const float*)d_in[3];
    const float* bw = (const float*)d_in[4];
    float* out = (float*)d_out;

    const int BT = in_sizes[0] / D_DIM;              // 8*4096 = 32768 rows
    const int blocks = (BT + ROWS_PER_BLOCK - 1) / ROWS_PER_BLOCK;
    hipLaunchKernelGGL(clifford_kernel, dim3(blocks), dim3(256), 0, stream,
                       x, gw, gb, sw, bw, out, BT);
}

// Round 2
// 244.881 us; speedup vs baseline: 1.0472x; 1.0472x over previous
//
#include <hip/hip_runtime.h>
#include <math.h>

// out = x + gate * ( sb*wedge(x, csum) + e0 * ss*scalar(x, csum) )
// where csum = c1+c2+c4 = 3*x[t] - x[t-1] - x[t-2] - x[t-4]  (wedge/scalar are
// linear in c, so the 3 shifts collapse into one evaluation).
//
// Layout: one wave (64 lanes) per (b,t) row. Lane handles float4s at
// q = lane + 64*m, m=0..3  -> every global load/store is 64 lanes x 16 B
// CONTIGUOUS (1 KB per wave instruction). Round-1 kernel had lane-stride-64B
// loads (64 cache lines per instr) and was TA/L1 serialization bound at
// 2.8 TB/s.
//
// A quad of lanes 4c..4c+3 co-owns chunk (c+16m): blades 4*sub..4*sub+3.
// Cross-blade values (blades 1,2,4,8 of x and csum) come from quad-broadcast
// ds_swizzle (no LDS, no barriers). Row reductions (gate dot, scalar) are
// 6-step wave butterflies.

constexpr int T_DIM = 4096;
constexpr int D_DIM = 1024;

// ds_swizzle quad-perm broadcast patterns: offset[15]=1, offset[7:0]=2-bit sels
constexpr int QB0 = 0x8000;  // all quad lanes <- quad lane 0
constexpr int QB1 = 0x8055;  // all quad lanes <- quad lane 1
constexpr int QB2 = 0x80AA;  // all quad lanes <- quad lane 2

template <int PAT>
__device__ __forceinline__ float swz(float v) {
    return __int_as_float(__builtin_amdgcn_ds_swizzle(__float_as_int(v), PAT));
}

__device__ __forceinline__ float sigmoidf(float z) {
    return 1.0f / (1.0f + __expf(-z));
}

__global__ __launch_bounds__(256) void clifford_kernel(
    const float* __restrict__ x,
    const float* __restrict__ gate_w,
    const float* __restrict__ gate_b,
    const float* __restrict__ scalar_w,
    const float* __restrict__ bivec_w,
    float* __restrict__ out,
    int BT)
{
    // XCD-aware swizzle: give each XCD a contiguous span of rows so the
    // t-1/t-2/t-4 re-reads hit the same XCD's L2 (heuristic only; correctness
    // independent of mapping).
    int blk = blockIdx.x;
    if ((gridDim.x & 7) == 0) {
        const int per = gridDim.x >> 3;
        blk = (blockIdx.x & 7) * per + (blockIdx.x >> 3);
    }

    const int lane = threadIdx.x & 63;
    const int row  = blk * 4 + (threadIdx.x >> 6);
    if (row >= BT) return;
    const int b = row >> 12;            // row / T_DIM
    const int t = row & (T_DIM - 1);
    const int sub = lane & 3;           // position within quad = blade group

    const float ss = sigmoidf(scalar_w[0]);
    const float sb = sigmoidf(bivec_w[0]);
    const float gb = gate_b[0];

    const float* __restrict__ r0 = x + (size_t)row * D_DIM;
    const size_t brow = (size_t)b * T_DIM;
    const float* __restrict__ r1 = x + (brow + ((t - 1) & (T_DIM - 1))) * D_DIM;
    const float* __restrict__ r2 = x + (brow + ((t - 2) & (T_DIM - 1))) * D_DIM;
    const float* __restrict__ r4 = x + (brow + ((t - 4) & (T_DIM - 1))) * D_DIM;

    // C0 diagonal signs for this lane's 4 blades (blades 4*sub .. 4*sub+3);
    // full table: {1,1,1,-1, 1,-1,-1,-1, -1,1,1,1, 1,1,1,-1}
    float4 ws;
    if      (sub == 0) ws = make_float4( 1.f,  1.f,  1.f, -1.f);
    else if (sub == 1) ws = make_float4( 1.f, -1.f, -1.f, -1.f);
    else if (sub == 2) ws = make_float4(-1.f,  1.f,  1.f,  1.f);
    else               ws = make_float4( 1.f,  1.f,  1.f, -1.f);
    // which wedge blades land in this lane's 4 elements
    const float m3  = (sub == 0) ? 1.f : 0.f;   // elem3 <- k=3
    const float a1  = (sub == 1) ? 1.f : 0.f;   // elem1<-k=5, elem2<-k=6
    const float a2  = (sub == 2) ? 1.f : 0.f;   // elem1<-k=9, elem2<-k=10
    const float m12 = (sub == 3) ? 1.f : 0.f;   // elem0 <- k=12

    float4 xs[4], dl[4];
    float gate_part = 0.f, sc_part = 0.f;

    #pragma unroll
    for (int m = 0; m < 4; ++m) {
        const int off = (lane << 2) + (m << 8);   // lane*4 + m*256 floats
        const float4 xv = *(const float4*)(r0 + off);
        const float4 p1 = *(const float4*)(r1 + off);
        const float4 p2 = *(const float4*)(r2 + off);
        const float4 p4 = *(const float4*)(r4 + off);
        const float4 gv = *(const float4*)(gate_w + off);
        xs[m] = xv;

        float4 cs;   // csum = 3x - x[t-1] - x[t-2] - x[t-4]
        cs.x = 3.f * xv.x - p1.x - p2.x - p4.x;
        cs.y = 3.f * xv.y - p1.y - p2.y - p4.y;
        cs.z = 3.f * xv.z - p1.z - p2.z - p4.z;
        cs.w = 3.f * xv.w - p1.w - p2.w - p4.w;

        gate_part += xv.x * gv.x + xv.y * gv.y + xv.z * gv.z + xv.w * gv.w;
        sc_part   += ws.x * (xv.x * cs.x) + ws.y * (xv.y * cs.y)
                   + ws.z * (xv.z * cs.z) + ws.w * (xv.w * cs.w);

        // blades 1,2,4,8 of this quad's chunk, for x and csum
        const float x1 = swz<QB0>(xv.y), x2 = swz<QB0>(xv.z);
        const float x4b = swz<QB1>(xv.x), x8b = swz<QB2>(xv.x);
        const float c1 = swz<QB0>(cs.y), c2 = swz<QB0>(cs.z);
        const float c4b = swz<QB1>(cs.x), c8b = swz<QB2>(cs.x);

        const float w3  = x1 * c2  - x2  * c1;    // k=3  (e12)
        const float w5  = x1 * c4b - x4b * c1;    // k=5  (e13)
        const float w6  = x2 * c4b - x4b * c2;    // k=6  (e23)
        const float w9  = x1 * c8b - x8b * c1;    // k=9  (e14)
        const float w10 = x2 * c8b - x8b * c2;    // k=10 (e24)
        const float w12 = x4b * c8b - x8b * c4b;  // k=12 (e34)

        dl[m] = make_float4(m12 * w12,
                            a1 * w5 + a2 * w9,
                            a1 * w6 + a2 * w10,
                            m3 * w3);
    }

    // wave == row: butterfly reduce gate dot + scalar over 64 lanes
    #pragma unroll
    for (int o = 32; o > 0; o >>= 1) {
        gate_part += __shfl_xor(gate_part, o, 64);
        sc_part   += __shfl_xor(sc_part,   o, 64);
    }
    const float gate = sigmoidf(gate_part + gb);
    const float gsb  = gate * sb;

    float* __restrict__ orow = out + (size_t)row * D_DIM;
    #pragma unroll
    for (int m = 0; m < 4; ++m) {
        float4 o4;
        o4.x = xs[m].x + gsb * dl[m].x;
        o4.y = xs[m].y + gsb * dl[m].y;
        o4.z = xs[m].z + gsb * dl[m].z;
        o4.w = xs[m].w + gsb * dl[m].w;
        if (m == 0 && lane == 0) o4.x += gate * ss * sc_part;  // d==0
        *(float4*)(orow + (lane << 2) + (m << 8)) = o4;
    }
}

extern "C" void kernel_launch(void* const* d_in, const int* in_sizes, int n_in,
                              void* d_out, int out_size, void* d_ws, size_t ws_size,
                              hipStream_t stream) {
    const float* x  = (const float*)d_in[0];
    const float* gw = (const float*)d_in[1];
    const float* gb = (const float*)d_in[2];
    const float* sw = (const float*)d_in[3];
    const float* bw = (const float*)d_in[4];
    float* out = (float*)d_out;

    const int BT = in_sizes[0] / D_DIM;              // 8*4096 = 32768 rows
    const int blocks = (BT + 3) / 4;                 // 4 rows (waves) per block
    hipLaunchKernelGGL(clifford_kernel, dim3(blocks), dim3(256), 0, stream,
                       x, gw, gb, sw, bw, out, BT);
}

// Round 3
// 241.355 us; speedup vs baseline: 1.0625x; 1.0146x over previous
//
#include <hip/hip_runtime.h>
#include <math.h>

// out = x + gate * ( sb*wedge(x, csum) + e0 * ss*scalar(x, csum) )
// csum = 3*x[t] - x[t-1] - x[t-2] - x[t-4]  (linearity collapses the 3 shifts).
//
// Layout: one wave per (b,t) row; lane handles float4s at lane + 64*m (m=0..3)
// -> all global accesses are 64x16B contiguous (1 KB/instr). Quad 4c..4c+3
// co-owns chunk; cross-blade values via quad-broadcast ds_swizzle.
//
// R3 change: ALL 20 loads hoisted before compute + __launch_bounds__(256,4)
// (VGPR cap 128). R2 had VGPR=44 -> compiler serialized load/use per m-iter
// (4 exposed memory latencies per wave); both pipes idle (<25%), latency-bound
// at 85 us. One exposed latency + full MLP should approach the ~42 us
// read+write floor.

constexpr int T_DIM = 4096;
constexpr int D_DIM = 1024;

// ds_swizzle quad-perm broadcast patterns: offset[15]=1, offset[7:0]=2-bit sels
constexpr int QB0 = 0x8000;  // all quad lanes <- quad lane 0
constexpr int QB1 = 0x8055;  // all quad lanes <- quad lane 1
constexpr int QB2 = 0x80AA;  // all quad lanes <- quad lane 2

template <int PAT>
__device__ __forceinline__ float swz(float v) {
    return __int_as_float(__builtin_amdgcn_ds_swizzle(__float_as_int(v), PAT));
}

__device__ __forceinline__ float sigmoidf(float z) {
    return 1.0f / (1.0f + __expf(-z));
}

__global__ __launch_bounds__(256, 4) void clifford_kernel(
    const float* __restrict__ x,
    const float* __restrict__ gate_w,
    const float* __restrict__ gate_b,
    const float* __restrict__ scalar_w,
    const float* __restrict__ bivec_w,
    float* __restrict__ out,
    int BT)
{
    // XCD-aware swizzle: contiguous row span per XCD so t-1/t-2/t-4 re-reads
    // hit the same XCD's L2 (perf heuristic only).
    int blk = blockIdx.x;
    if ((gridDim.x & 7) == 0) {
        const int per = gridDim.x >> 3;
        blk = (blockIdx.x & 7) * per + (blockIdx.x >> 3);
    }

    const int lane = threadIdx.x & 63;
    const int row  = blk * 4 + (threadIdx.x >> 6);
    if (row >= BT) return;
    const int b = row >> 12;
    const int t = row & (T_DIM - 1);
    const int sub = lane & 3;

    const float* __restrict__ r0 = x + (size_t)row * D_DIM;
    const size_t brow = (size_t)b * T_DIM;
    const float* __restrict__ r1 = x + (brow + ((t - 1) & (T_DIM - 1))) * D_DIM;
    const float* __restrict__ r2 = x + (brow + ((t - 2) & (T_DIM - 1))) * D_DIM;
    const float* __restrict__ r4 = x + (brow + ((t - 4) & (T_DIM - 1))) * D_DIM;

    // ---- issue ALL global loads up front (20 dwordx4 in flight) ----
    float4 xv[4], q1[4], q2[4], q4[4], gv[4];
    #pragma unroll
    for (int m = 0; m < 4; ++m) {
        const int off = (lane << 2) + (m << 8);
        xv[m] = *(const float4*)(r0 + off);
        q1[m] = *(const float4*)(r1 + off);
        q2[m] = *(const float4*)(r2 + off);
        q4[m] = *(const float4*)(r4 + off);
        gv[m] = *(const float4*)(gate_w + off);
    }

    const float ss = sigmoidf(scalar_w[0]);
    const float sb = sigmoidf(bivec_w[0]);
    const float gb = gate_b[0];

    // C0 diagonal signs for this lane's 4 blades (full table:
    // {1,1,1,-1, 1,-1,-1,-1, -1,1,1,1, 1,1,1,-1})
    float4 ws;
    if      (sub == 0) ws = make_float4( 1.f,  1.f,  1.f, -1.f);
    else if (sub == 1) ws = make_float4( 1.f, -1.f, -1.f, -1.f);
    else if (sub == 2) ws = make_float4(-1.f,  1.f,  1.f,  1.f);
    else               ws = make_float4( 1.f,  1.f,  1.f, -1.f);
    const float m3  = (sub == 0) ? 1.f : 0.f;   // elem3 <- k=3
    const float a1  = (sub == 1) ? 1.f : 0.f;   // elem1<-k=5, elem2<-k=6
    const float a2  = (sub == 2) ? 1.f : 0.f;   // elem1<-k=9, elem2<-k=10
    const float m12 = (sub == 3) ? 1.f : 0.f;   // elem0 <- k=12

    float gate_part = 0.f, sc_part = 0.f;
    float4 dl[4];

    #pragma unroll
    for (int m = 0; m < 4; ++m) {
        float4 cs;   // csum = 3x - x[t-1] - x[t-2] - x[t-4]
        cs.x = 3.f * xv[m].x - q1[m].x - q2[m].x - q4[m].x;
        cs.y = 3.f * xv[m].y - q1[m].y - q2[m].y - q4[m].y;
        cs.z = 3.f * xv[m].z - q1[m].z - q2[m].z - q4[m].z;
        cs.w = 3.f * xv[m].w - q1[m].w - q2[m].w - q4[m].w;

        gate_part += xv[m].x * gv[m].x + xv[m].y * gv[m].y
                   + xv[m].z * gv[m].z + xv[m].w * gv[m].w;
        sc_part   += ws.x * (xv[m].x * cs.x) + ws.y * (xv[m].y * cs.y)
                   + ws.z * (xv[m].z * cs.z) + ws.w * (xv[m].w * cs.w);

        const float x1  = swz<QB0>(xv[m].y), x2  = swz<QB0>(xv[m].z);
        const float x4b = swz<QB1>(xv[m].x), x8b = swz<QB2>(xv[m].x);
        const float c1  = swz<QB0>(cs.y),    c2  = swz<QB0>(cs.z);
        const float c4b = swz<QB1>(cs.x),    c8b = swz<QB2>(cs.x);

        const float w3  = x1 * c2  - x2  * c1;    // k=3  (e12)
        const float w5  = x1 * c4b - x4b * c1;    // k=5  (e13)
        const float w6  = x2 * c4b - x4b * c2;    // k=6  (e23)
        const float w9  = x1 * c8b - x8b * c1;    // k=9  (e14)
        const float w10 = x2 * c8b - x8b * c2;    // k=10 (e24)
        const float w12 = x4b * c8b - x8b * c4b;  // k=12 (e34)

        dl[m] = make_float4(m12 * w12,
                            a1 * w5 + a2 * w9,
                            a1 * w6 + a2 * w10,
                            m3 * w3);
    }

    // wave == row: butterfly reduce gate dot + scalar over 64 lanes
    #pragma unroll
    for (int o = 32; o > 0; o >>= 1) {
        gate_part += __shfl_xor(gate_part, o, 64);
        sc_part   += __shfl_xor(sc_part,   o, 64);
    }
    const float gate = sigmoidf(gate_part + gb);
    const float gsb  = gate * sb;

    float* __restrict__ orow = out + (size_t)row * D_DIM;
    #pragma unroll
    for (int m = 0; m < 4; ++m) {
        float4 o4;
        o4.x = xv[m].x + gsb * dl[m].x;
        o4.y = xv[m].y + gsb * dl[m].y;
        o4.z = xv[m].z + gsb * dl[m].z;
        o4.w = xv[m].w + gsb * dl[m].w;
        if (m == 0 && lane == 0) o4.x += gate * ss * sc_part;  // d==0
        *(float4*)(orow + (lane << 2) + (m << 8)) = o4;
    }
}

extern "C" void kernel_launch(void* const* d_in, const int* in_sizes, int n_in,
                              void* d_out, int out_size, void* d_ws, size_t ws_size,
                              hipStream_t stream) {
    const float* x  = (const float*)d_in[0];
    const float* gw = (const float*)d_in[1];
    const float* gb = (const float*)d_in[2];
    const float* sw = (const float*)d_in[3];
    const float* bw = (const float*)d_in[4];
    float* out = (float*)d_out;

    const int BT = in_sizes[0] / D_DIM;              // 8*4096 = 32768 rows
    const int blocks = (BT + 3) / 4;                 // 4 rows (waves) per block
    hipLaunchKernelGGL(clifford_kernel, dim3(blocks), dim3(256), 0, stream,
                       x, gw, gb, sw, bw, out, BT);
}